// Round 8
// baseline (1338.457 us; speedup 1.0000x reference)
//
#include <hip/hip_runtime.h>

// SymmetricRBM — round 13: register-window LDS-read reduction, spill-capped.
// Round-12 post-mortem: removing bank conflicts + bfe thinning = no change
// (1025->1056 us) -> conflicts were slack. Remaining theory: LDS-pipe load
// from 8x-redundant ds_read_b128 (1024/step/wave, ~650-850 us of pipe
// occupancy) sits beside ~VALU-saturation. Windows fix it but spilled twice
// at 64acc+32win; this round caps live regs ~85:
//  * G1 in two ii-blocks of 4: acc[2][4][4]=32 + win[4]=16 per block, block
//    sampled before the next starts. Reads 512->140/pass.
//  * G2 single 8-row window (rows per mm are 8 consecutive): win[8]=32 +
//    wh[2][8]=16. Reads 512->78/pass. Extraction still shared across 8 ii.
// Per step 1024->218 reads. FMA order per accumulator unchanged (m ascending,
// w0 then w1, same expression shapes) -> bit-exact samples.
// Gates: WRITE_SIZE ~1 MB (spill tell), conflicts ~0, VGPR<=128.

#define KSTEPS 10
#define HALF_H 8388608u   // (65536*4*64)/2
#define HALF_V 2097152u   // (65536*64)/2

__device__ __forceinline__ void tf20(unsigned int k0, unsigned int k1,
                                     unsigned int x0, unsigned int x1,
                                     unsigned int &o0, unsigned int &o1)
{
  unsigned int k2 = k0 ^ k1 ^ 0x1BD11BDAu;
  x0 += k0; x1 += k1;
#define TFR(rot) { x0 += x1; x1 = (x1 << (rot)) | (x1 >> (32 - (rot))); x1 ^= x0; }
  TFR(13) TFR(15) TFR(26) TFR(6)
  x0 += k1; x1 += k2 + 1u;
  TFR(17) TFR(29) TFR(16) TFR(24)
  x0 += k2; x1 += k0 + 2u;
  TFR(13) TFR(15) TFR(26) TFR(6)
  x0 += k0; x1 += k1 + 3u;
  TFR(17) TFR(29) TFR(16) TFR(24)
  x0 += k1; x1 += k2 + 4u;
  TFR(13) TFR(15) TFR(26) TFR(6)
  x0 += k2; x1 += k0 + 5u;
#undef TFR
  o0 = x0; o1 = x1;
}

__device__ __forceinline__ float u01(unsigned int bits) {
  return __uint_as_float((bits >> 9) | 0x3F800000u) - 1.0f;
}

__device__ __forceinline__ float softplusf(float x) {
  return fmaxf(x, 0.0f) + log1pf(expf(-fabsf(x)));
}

__global__ void init_ws_kernel(float* ws) { ws[0] = 0.0f; }

__global__ __launch_bounds__(256, 2)
void rbm_valu_kernel(const float* __restrict__ vdat,
                     const float* __restrict__ kf,
                     const float* __restrict__ bsp,
                     const float* __restrict__ cvp,
                     float* __restrict__ ws)
{
  // 8 staggered copies, stride 129 rows (2064 B == 16 mod 128). Lane q reads
  // copy q; within an octet all 8 lanes read the same address (broadcast);
  // across octets bank-group offsets 0,4,...,28 -> all 32 banks once.
  // (Verified round 12: SQ_LDS_BANK_CONFLICT == 0 with this stagger.)
  __shared__ __align__(16) float kd2[8][129][4];   // kd2[c][z][a] = kf[a*64+(z&63)]
  __shared__ unsigned int sK[4][KSTEPS];           // kh0,kh1,kv0,kv1 per step

  const int tid = threadIdx.x;                     // 0..255
  const int gthread = blockIdx.x * 256 + tid;      // 0..262143
  const int pair = gthread >> 3;                   // rows (pair, pair+32768)
  const int q = gthread & 7;                       // i-eighth
  const int i0 = 8 * q;

  if (tid == 0) {
    unsigned int c0 = 0u, c1 = 42u;
    for (int t = 0; t < KSTEPS; ++t) {
      unsigned int Aa, Ab, Ba, Bb, Ca, Cb;
      tf20(c0, c1, 0u, 3u, Aa, Ab);
      tf20(c0, c1, 1u, 4u, Ba, Bb);
      tf20(c0, c1, 2u, 5u, Ca, Cb);
      sK[0][t] = Ca; sK[1][t] = Ab;   // kh
      sK[2][t] = Bb; sK[3][t] = Cb;   // kv
      c0 = Aa; c1 = Ba;               // next k
    }
  }
  for (int idx = tid; idx < 8 * 129; idx += 256) {
    const int cc = idx / 129;
    const int z = idx % 129;
    const int zz = z & 63;
    kd2[cc][z][0] = kf[zz];
    kd2[cc][z][1] = kf[64 + zz];
    kd2[cc][z][2] = kf[128 + zz];
    kd2[cc][z][3] = kf[192 + zz];
  }
  __syncthreads();

  const float4* kr = (const float4*)&kd2[q][0][0];   // kr[row] = 16B row

  // ---- load both rows of the pair as 2x32-bit masks each ----
  unsigned int vw[2][2];                           // [row][word]
  for (int r = 0; r < 2; ++r) {
    const float* vp = vdat + (size_t)(pair + r * 32768) * 64;
    unsigned int w0 = 0u, w1 = 0u;
#pragma unroll
    for (int j = 0; j < 32; j += 4) {
      float4 f = *(const float4*)(vp + j);
      w0 |= ((unsigned int)(f.x != 0.0f)) << (j + 0);
      w0 |= ((unsigned int)(f.y != 0.0f)) << (j + 1);
      w0 |= ((unsigned int)(f.z != 0.0f)) << (j + 2);
      w0 |= ((unsigned int)(f.w != 0.0f)) << (j + 3);
      float4 g = *(const float4*)(vp + 32 + j);
      w1 |= ((unsigned int)(g.x != 0.0f)) << (j + 0);
      w1 |= ((unsigned int)(g.y != 0.0f)) << (j + 1);
      w1 |= ((unsigned int)(g.z != 0.0f)) << (j + 2);
      w1 |= ((unsigned int)(g.w != 0.0f)) << (j + 3);
    }
    vw[r][0] = w0; vw[r][1] = w1;
  }

  const float bs = bsp[0];
  const float cv[4] = {cvp[0], cvp[1], cvp[2], cvp[3]};

  float fe = 0.0f;
  if (q == 0)   // term1 of fe_data, once per pair
    fe -= bs * (float)(__popc(vw[0][0]) + __popc(vw[0][1]) +
                       __popc(vw[1][0]) + __popc(vw[1][1]));

  unsigned int hw[2][2][4];   // [word][row][a] — full h masks after exchange

  for (int step = 0; step <= KSTEPS; ++step) {
    const bool fe_pass   = (step == KSTEPS);
    const bool data_pass = (step == 0);
    const unsigned int kh0 = sK[0][fe_pass ? 0 : step];
    const unsigned int kh1 = sK[1][fe_pass ? 0 : step];

    unsigned int hmy[2][4] = {{0u,0u,0u,0u},{0u,0u,0u,0u}};

    // ---- G1 in two ii-blocks of 4, each with a 4-row rolling window ----
    // row(ir, mm, w, blk) = 32w + mm - (i0 + 4blk + ir) + 64 = basek + mm - ir
#pragma unroll 1
    for (int blk = 0; blk < 2; ++blk) {
      float acc[2][4][4] = {};
#pragma unroll
      for (int w = 0; w < 2; ++w) {
        const unsigned int b0 = vw[0][w], b1 = vw[1][w];
        const int basek = 32 * w - i0 - 4 * blk + 64;
        float4 win[4];
        win[1] = kr[basek - 3];    // slot t&3 holds row basek+t (t = mm-ir)
        win[2] = kr[basek - 2];
        win[3] = kr[basek - 1];
        for (int mmo = 0; mmo < 32; mmo += 4) {
#pragma unroll
          for (int u = 0; u < 4; ++u) {
            const int mm = mmo + u;
            win[u] = kr[basek + mm];           // t = mm, slot mm&3 = u
            const float f0 = (float)((b0 >> mm) & 1u);
            const float f1 = (float)((b1 >> mm) & 1u);
#pragma unroll
            for (int ir = 0; ir < 4; ++ir) {
              const float4 kv = win[(u - ir) & 3];   // row basek+mm-ir
              acc[0][0][ir] += f0 * kv.x; acc[0][1][ir] += f0 * kv.y;
              acc[0][2][ir] += f0 * kv.z; acc[0][3][ir] += f0 * kv.w;
              acc[1][0][ir] += f1 * kv.x; acc[1][1][ir] += f1 * kv.y;
              acc[1][2][ir] += f1 * kv.z; acc[1][3][ir] += f1 * kv.w;
            }
          }
        }
      }

      if (fe_pass || data_pass) {   // term2 = -sum softplus(wv + c)
#pragma unroll
        for (int ir = 0; ir < 4; ++ir) {
          float s = 0.0f;
#pragma unroll
          for (int a = 0; a < 4; ++a) {
            float x0 = acc[0][a][ir] + cv[a];
            float x1 = acc[1][a][ir] + cv[a];
            s += softplusf(x0) + softplusf(x1);
          }
          fe += fe_pass ? s : -s;
        }
      }
      if (!fe_pass) {
        // ---- sample h for this block's 4 i's ----
#pragma unroll
        for (int ir = 0; ir < 4; ++ir) {
          const int iia = 4 * blk + ir;
          const unsigned int base = (unsigned int)pair * 256u +
                                    (unsigned int)(i0 + iia);
#pragma unroll
          for (int a = 0; a < 4; ++a) {
            float x0 = acc[0][a][ir] + cv[a];
            float x1 = acc[1][a][ir] + cv[a];
            unsigned int cnt = base + (unsigned int)a * 64u;
            unsigned int r0, r1; tf20(kh0, kh1, cnt, cnt + HALF_H, r0, r1);
            float u0 = u01(r0), u1 = u01(r1);
            float e0 = __expf(-x0), e1 = __expf(-x1);
            hmy[0][a] |= ((fmaf(u0, e0, u0) < 1.0f) ? 1u : 0u) << iia;
            hmy[1][a] |= ((fmaf(u1, e1, u1) < 1.0f) ? 1u : 0u) << iia;
          }
        }
      }
    }
    if (fe_pass) break;

    // ---- exchange: assemble full 64-bit h masks across the 8 q-lanes ----
#pragma unroll
    for (int r = 0; r < 2; ++r)
#pragma unroll
      for (int a = 0; a < 4; ++a) {
        unsigned int my = hmy[r][a];
        unsigned int p1 = (unsigned int)__shfl_xor((int)my, 1);
        unsigned int v16 = (q & 1) ? (p1 | (my << 8)) : (my | (p1 << 8));
        unsigned int p2 = (unsigned int)__shfl_xor((int)v16, 2);
        unsigned int v32 = (q & 2) ? (p2 | (v16 << 16)) : (v16 | (p2 << 16));
        unsigned int p3 = (unsigned int)__shfl_xor((int)v32, 4);
        hw[0][r][a] = (q & 4) ? p3 : v32;
        hw[1][r][a] = (q & 4) ? v32 : p3;
      }

    // ---- G2 with a single 8-row rolling window over all 8 ii ----
    // row(ii, mm, w) = (i0+ii) + 63 - 32w - mm = b2 - mm + ii; per mm the 8
    // needed rows are b2-mm .. b2-mm+7 -> one new row per mm.
    const unsigned int kv0 = sK[2][step], kv1 = sK[3][step];
    float wh[2][8] = {};
#pragma unroll
    for (int w = 0; w < 2; ++w) {
      const unsigned int tA0 = hw[w][0][0], tA1 = hw[w][0][1];
      const unsigned int tA2 = hw[w][0][2], tA3 = hw[w][0][3];
      const unsigned int tB0 = hw[w][1][0], tB1 = hw[w][1][1];
      const unsigned int tB2 = hw[w][1][2], tB3 = hw[w][1][3];
      const int b2 = i0 + 63 - 32 * w;
      float4 win[8];                 // slot t&7 holds row b2-t (t = mm-j)
      win[7] = kr[b2 + 1];
      win[6] = kr[b2 + 2];
      win[5] = kr[b2 + 3];
      win[4] = kr[b2 + 4];
      win[3] = kr[b2 + 5];
      win[2] = kr[b2 + 6];
      win[1] = kr[b2 + 7];
      for (int mmo = 0; mmo < 32; mmo += 8) {
#pragma unroll
        for (int u = 0; u < 8; ++u) {
          const int mm = mmo + u;
          win[u] = kr[b2 - mm];                  // t = mm, slot mm&7 = u
          const float fA0 = (float)((tA0 >> mm) & 1u);
          const float fA1 = (float)((tA1 >> mm) & 1u);
          const float fA2 = (float)((tA2 >> mm) & 1u);
          const float fA3 = (float)((tA3 >> mm) & 1u);
          const float fB0 = (float)((tB0 >> mm) & 1u);
          const float fB1 = (float)((tB1 >> mm) & 1u);
          const float fB2 = (float)((tB2 >> mm) & 1u);
          const float fB3 = (float)((tB3 >> mm) & 1u);
#pragma unroll
          for (int ir = 0; ir < 4; ++ir) {
            const float4 kvA = win[(u - ir) & 7];      // row b2-mm+ir
            wh[0][ir] += fA0 * kvA.x + fA1 * kvA.y + fA2 * kvA.z + fA3 * kvA.w;
            wh[1][ir] += fB0 * kvA.x + fB1 * kvA.y + fB2 * kvA.z + fB3 * kvA.w;
            const float4 kvB = win[(u - ir - 4) & 7];  // row b2-mm+ir+4
            wh[0][ir + 4] += fA0 * kvB.x + fA1 * kvB.y + fA2 * kvB.z + fA3 * kvB.w;
            wh[1][ir + 4] += fB0 * kvB.x + fB1 * kvB.y + fB2 * kvB.z + fB3 * kvB.w;
          }
        }
      }
    }

    // ---- sample v for my 8 i's ----
    unsigned int vmy[2] = {0u, 0u};
#pragma unroll
    for (int ii = 0; ii < 8; ++ii) {
      unsigned int cnt = (unsigned int)pair * 64u + (unsigned int)(i0 + ii);
      unsigned int r0, r1; tf20(kv0, kv1, cnt, cnt + HALF_V, r0, r1);
      float u0 = u01(r0), u1 = u01(r1);
      float e0 = __expf(-(wh[0][ii] + bs)), e1 = __expf(-(wh[1][ii] + bs));
      vmy[0] |= ((fmaf(u0, e0, u0) < 1.0f) ? 1u : 0u) << ii;
      vmy[1] |= ((fmaf(u1, e1, u1) < 1.0f) ? 1u : 0u) << ii;
    }

    // ---- exchange: assemble full v masks ----
#pragma unroll
    for (int r = 0; r < 2; ++r) {
      unsigned int my = vmy[r];
      unsigned int p1 = (unsigned int)__shfl_xor((int)my, 1);
      unsigned int v16 = (q & 1) ? (p1 | (my << 8)) : (my | (p1 << 8));
      unsigned int p2 = (unsigned int)__shfl_xor((int)v16, 2);
      unsigned int v32 = (q & 2) ? (p2 | (v16 << 16)) : (v16 | (p2 << 16));
      unsigned int p3 = (unsigned int)__shfl_xor((int)v32, 4);
      vw[r][0] = (q & 4) ? p3 : v32;
      vw[r][1] = (q & 4) ? v32 : p3;
    }
  }

  // term1 of fe_model, once per pair
  if (q == 0)
    fe += bs * (float)(__popc(vw[0][0]) + __popc(vw[0][1]) +
                       __popc(vw[1][0]) + __popc(vw[1][1]));

  // wave reduction, one atomic per wave
  for (int off = 32; off > 0; off >>= 1) fe += __shfl_down(fe, off);
  if ((tid & 63) == 0) atomicAdd(ws, fe);
}

__global__ void fin_kernel(const float* __restrict__ ws, float* __restrict__ out) {
  out[0] = ws[0] * (1.0f / 65536.0f);
}

extern "C" void kernel_launch(void* const* d_in, const int* in_sizes, int n_in,
                              void* d_out, int out_size, void* d_ws, size_t ws_size,
                              hipStream_t stream)
{
  (void)in_sizes; (void)n_in; (void)out_size; (void)ws_size;
  const float* vdat = (const float*)d_in[0];
  const float* kf   = (const float*)d_in[1];
  const float* bsp  = (const float*)d_in[2];
  const float* cvp  = (const float*)d_in[3];
  float* out = (float*)d_out;
  float* ws  = (float*)d_ws;

  init_ws_kernel<<<dim3(1), dim3(1), 0, stream>>>(ws);
  rbm_valu_kernel<<<dim3(1024), dim3(256), 0, stream>>>(vdat, kf, bsp, cvp, ws);
  fin_kernel<<<dim3(1), dim3(1), 0, stream>>>(ws, out);
}

// Round 10
// 1028.847 us; speedup vs baseline: 1.3009x; 1.3009x over previous
//
#include <hip/hip_runtime.h>

// SymmetricRBM — round 15: byte-identical resubmit of round 14 (= round-10
// anchor, 1025 us verified). Round-14 hit the same container-level double
// fault as round 7 ("MI355X container failed twice", no kernel diagnostics);
// round 8's identical resubmit then ran fine -> infra flake, resubmit.
// Ledger (all harness-verified, absmax 0.0): r10 1025us (this code) /
// r12 1056 (bfe+8copy, conflicts->0, no gain) / windows r9/r11/r13 all
// spill-regressed (compiler software-pipelines ds_reads past FMAs, live set
// blows the 128-VGPR cap). Healthy config: VALUBusy 85-93%, no spill,
// 16 waves/CU (VGPR-capped), conflicts free/zero. Instruction stream:
// ~86k FMA (exact MAC count of dense circulant matvecs, fp32 ascending-m
// order required for bit-exact Gibbs chain) + ~34k threefry (JAX 20-round
// spec) + ~30k extract/sample. VALU-pipe floor at sustained clock ~= the
// measured 1025 us -> roofline once re-verified.

#define KSTEPS 10
#define HALF_H 8388608u   // (65536*4*64)/2
#define HALF_V 2097152u   // (65536*64)/2

__device__ __forceinline__ void tf20(unsigned int k0, unsigned int k1,
                                     unsigned int x0, unsigned int x1,
                                     unsigned int &o0, unsigned int &o1)
{
  unsigned int k2 = k0 ^ k1 ^ 0x1BD11BDAu;
  x0 += k0; x1 += k1;
#define TFR(rot) { x0 += x1; x1 = (x1 << (rot)) | (x1 >> (32 - (rot))); x1 ^= x0; }
  TFR(13) TFR(15) TFR(26) TFR(6)
  x0 += k1; x1 += k2 + 1u;
  TFR(17) TFR(29) TFR(16) TFR(24)
  x0 += k2; x1 += k0 + 2u;
  TFR(13) TFR(15) TFR(26) TFR(6)
  x0 += k0; x1 += k1 + 3u;
  TFR(17) TFR(29) TFR(16) TFR(24)
  x0 += k1; x1 += k2 + 4u;
  TFR(13) TFR(15) TFR(26) TFR(6)
  x0 += k2; x1 += k0 + 5u;
#undef TFR
  o0 = x0; o1 = x1;
}

__device__ __forceinline__ float u01(unsigned int bits) {
  return __uint_as_float((bits >> 9) | 0x3F800000u) - 1.0f;
}

__device__ __forceinline__ float softplusf(float x) {
  return fmaxf(x, 0.0f) + log1pf(expf(-fabsf(x)));
}

__global__ void init_ws_kernel(float* ws) { ws[0] = 0.0f; }

__global__ __launch_bounds__(256, 2)
void rbm_valu_kernel(const float* __restrict__ vdat,
                     const float* __restrict__ kf,
                     const float* __restrict__ bsp,
                     const float* __restrict__ cvp,
                     float* __restrict__ ws)
{
  // 4 staggered copies at 129-row stride (2064 B == 16 mod 128). 8 q-groups
  // of 8 lanes; groups {q, q+4} share copy q&3 with rows 32 apart (512 B ==
  // 0 mod 128) -> 2-way bank aliasing, which is free (m136). Within a group
  // all 8 lanes read the same address -> broadcast.
  __shared__ __align__(16) float kd2[4][129][4];   // kd2[c][z][a] = kf[a*64+(z&63)]
  __shared__ unsigned int sK[4][KSTEPS];           // kh0,kh1,kv0,kv1 per step

  const int tid = threadIdx.x;                     // 0..255
  const int gthread = blockIdx.x * 256 + tid;      // 0..262143
  const int pair = gthread >> 3;                   // rows (pair, pair+32768)
  const int q = gthread & 7;                       // i-eighth
  const int i0 = 8 * q;
  const int c = q & 3;

  if (tid == 0) {
    unsigned int c0 = 0u, c1 = 42u;
    for (int t = 0; t < KSTEPS; ++t) {
      unsigned int Aa, Ab, Ba, Bb, Ca, Cb;
      tf20(c0, c1, 0u, 3u, Aa, Ab);
      tf20(c0, c1, 1u, 4u, Ba, Bb);
      tf20(c0, c1, 2u, 5u, Ca, Cb);
      sK[0][t] = Ca; sK[1][t] = Ab;   // kh
      sK[2][t] = Bb; sK[3][t] = Cb;   // kv
      c0 = Aa; c1 = Ba;               // next k
    }
  }
  for (int idx = tid; idx < 4 * 129; idx += 256) {
    const int cc = idx / 129;
    const int z = idx % 129;
    const int zz = z & 63;
    kd2[cc][z][0] = kf[zz];
    kd2[cc][z][1] = kf[64 + zz];
    kd2[cc][z][2] = kf[128 + zz];
    kd2[cc][z][3] = kf[192 + zz];
  }
  __syncthreads();

  const float4* kr = (const float4*)&kd2[c][0][0];   // kr[row] = 16B row

  // ---- load both rows of the pair as 2x32-bit masks each ----
  unsigned int vw[2][2];                           // [row][word]
  for (int r = 0; r < 2; ++r) {
    const float* vp = vdat + (size_t)(pair + r * 32768) * 64;
    unsigned int w0 = 0u, w1 = 0u;
#pragma unroll
    for (int j = 0; j < 32; j += 4) {
      float4 f = *(const float4*)(vp + j);
      w0 |= ((unsigned int)(f.x != 0.0f)) << (j + 0);
      w0 |= ((unsigned int)(f.y != 0.0f)) << (j + 1);
      w0 |= ((unsigned int)(f.z != 0.0f)) << (j + 2);
      w0 |= ((unsigned int)(f.w != 0.0f)) << (j + 3);
      float4 g = *(const float4*)(vp + 32 + j);
      w1 |= ((unsigned int)(g.x != 0.0f)) << (j + 0);
      w1 |= ((unsigned int)(g.y != 0.0f)) << (j + 1);
      w1 |= ((unsigned int)(g.z != 0.0f)) << (j + 2);
      w1 |= ((unsigned int)(g.w != 0.0f)) << (j + 3);
    }
    vw[r][0] = w0; vw[r][1] = w1;
  }

  const float bs = bsp[0];
  const float cv[4] = {cvp[0], cvp[1], cvp[2], cvp[3]};

  float fe = 0.0f;
  if (q == 0)   // term1 of fe_data, once per pair
    fe -= bs * (float)(__popc(vw[0][0]) + __popc(vw[0][1]) +
                       __popc(vw[1][0]) + __popc(vw[1][1]));

  unsigned int hw[2][2][4];   // [word][row][a] — full h masks after exchange

  for (int step = 0; step <= KSTEPS; ++step) {
    const bool fe_pass   = (step == KSTEPS);
    const bool data_pass = (step == 0);
    const unsigned int kh0 = sK[0][fe_pass ? 0 : step];
    const unsigned int kh1 = sK[1][fe_pass ? 0 : step];

    // ---- G1: acc[row][a][ii] += f_m * k[a][(m-i)&63] ----
    // row(ii, mm, w) = 32w + mm - (i0+ii) + 64 = base + mm - ii
    float acc[2][4][8] = {};
#pragma unroll
    for (int w = 0; w < 2; ++w) {
      unsigned int b0 = vw[0][w], b1 = vw[1][w];
      const int base = 32 * w - i0 + 64;
#pragma unroll 4
      for (int mm = 0; mm < 32; ++mm) {
        float f0 = (float)(b0 & 1u); b0 >>= 1;
        float f1 = (float)(b1 & 1u); b1 >>= 1;
        const float4* kp = kr + (base + mm);
#pragma unroll
        for (int ii = 0; ii < 8; ++ii) {
          const float4 kv = kp[-ii];             // row base+mm-ii
          acc[0][0][ii] += f0 * kv.x; acc[0][1][ii] += f0 * kv.y;
          acc[0][2][ii] += f0 * kv.z; acc[0][3][ii] += f0 * kv.w;
          acc[1][0][ii] += f1 * kv.x; acc[1][1][ii] += f1 * kv.y;
          acc[1][2][ii] += f1 * kv.z; acc[1][3][ii] += f1 * kv.w;
        }
      }
    }

    if (fe_pass || data_pass) {   // term2 = -sum softplus(wv + c)
#pragma unroll
      for (int ii = 0; ii < 8; ++ii) {
        float s = 0.0f;
#pragma unroll
        for (int a = 0; a < 4; ++a) {
          float x0 = acc[0][a][ii] + cv[a];
          float x1 = acc[1][a][ii] + cv[a];
          s += softplusf(x0) + softplusf(x1);
        }
        fe += fe_pass ? s : -s;
      }
    }
    if (fe_pass) break;

    // ---- sample h for my 8 i's ----
    unsigned int hmy[2][4] = {{0u,0u,0u,0u},{0u,0u,0u,0u}};
#pragma unroll
    for (int ii = 0; ii < 8; ++ii) {
      const unsigned int base = (unsigned int)pair * 256u + (unsigned int)(i0 + ii);
#pragma unroll
      for (int a = 0; a < 4; ++a) {
        float x0 = acc[0][a][ii] + cv[a];
        float x1 = acc[1][a][ii] + cv[a];
        unsigned int cnt = base + (unsigned int)a * 64u;
        unsigned int r0, r1; tf20(kh0, kh1, cnt, cnt + HALF_H, r0, r1);
        float u0 = u01(r0), u1 = u01(r1);
        float e0 = __expf(-x0), e1 = __expf(-x1);
        hmy[0][a] |= ((fmaf(u0, e0, u0) < 1.0f) ? 1u : 0u) << ii;
        hmy[1][a] |= ((fmaf(u1, e1, u1) < 1.0f) ? 1u : 0u) << ii;
      }
    }

    // ---- exchange: assemble full 64-bit h masks across the 8 q-lanes ----
#pragma unroll
    for (int r = 0; r < 2; ++r)
#pragma unroll
      for (int a = 0; a < 4; ++a) {
        unsigned int my = hmy[r][a];
        unsigned int p1 = (unsigned int)__shfl_xor((int)my, 1);
        unsigned int v16 = (q & 1) ? (p1 | (my << 8)) : (my | (p1 << 8));
        unsigned int p2 = (unsigned int)__shfl_xor((int)v16, 2);
        unsigned int v32 = (q & 2) ? (p2 | (v16 << 16)) : (v16 | (p2 << 16));
        unsigned int p3 = (unsigned int)__shfl_xor((int)v32, 4);
        hw[0][r][a] = (q & 4) ? p3 : v32;
        hw[1][r][a] = (q & 4) ? v32 : p3;
      }

    // ---- G2: wh[row][ii] += sum_a f[a] * k[a][(i-1-m)&63] ----
    // row(ii, mm, w) = (i0+ii) + 63 - 32w - mm = base2 - mm + ii
    const unsigned int kv0 = sK[2][step], kv1 = sK[3][step];
    float wh[2][8] = {};
#pragma unroll
    for (int w = 0; w < 2; ++w) {
      unsigned int tA0 = hw[w][0][0], tA1 = hw[w][0][1];
      unsigned int tA2 = hw[w][0][2], tA3 = hw[w][0][3];
      unsigned int tB0 = hw[w][1][0], tB1 = hw[w][1][1];
      unsigned int tB2 = hw[w][1][2], tB3 = hw[w][1][3];
      const int base2 = i0 + 63 - 32 * w;
#pragma unroll 4
      for (int mm = 0; mm < 32; ++mm) {
        float fA0 = (float)(tA0 & 1u), fA1 = (float)(tA1 & 1u);
        float fA2 = (float)(tA2 & 1u), fA3 = (float)(tA3 & 1u);
        float fB0 = (float)(tB0 & 1u), fB1 = (float)(tB1 & 1u);
        float fB2 = (float)(tB2 & 1u), fB3 = (float)(tB3 & 1u);
        const float4* kp = kr + (base2 - mm);
#pragma unroll
        for (int ii = 0; ii < 8; ++ii) {
          const float4 kv = kp[ii];              // row base2-mm+ii
          wh[0][ii] += fA0 * kv.x + fA1 * kv.y + fA2 * kv.z + fA3 * kv.w;
          wh[1][ii] += fB0 * kv.x + fB1 * kv.y + fB2 * kv.z + fB3 * kv.w;
        }
        tA0 >>= 1; tA1 >>= 1; tA2 >>= 1; tA3 >>= 1;
        tB0 >>= 1; tB1 >>= 1; tB2 >>= 1; tB3 >>= 1;
      }
    }

    // ---- sample v for my 8 i's ----
    unsigned int vmy[2] = {0u, 0u};
#pragma unroll
    for (int ii = 0; ii < 8; ++ii) {
      unsigned int cnt = (unsigned int)pair * 64u + (unsigned int)(i0 + ii);
      unsigned int r0, r1; tf20(kv0, kv1, cnt, cnt + HALF_V, r0, r1);
      float u0 = u01(r0), u1 = u01(r1);
      float e0 = __expf(-(wh[0][ii] + bs)), e1 = __expf(-(wh[1][ii] + bs));
      vmy[0] |= ((fmaf(u0, e0, u0) < 1.0f) ? 1u : 0u) << ii;
      vmy[1] |= ((fmaf(u1, e1, u1) < 1.0f) ? 1u : 0u) << ii;
    }

    // ---- exchange: assemble full v masks ----
#pragma unroll
    for (int r = 0; r < 2; ++r) {
      unsigned int my = vmy[r];
      unsigned int p1 = (unsigned int)__shfl_xor((int)my, 1);
      unsigned int v16 = (q & 1) ? (p1 | (my << 8)) : (my | (p1 << 8));
      unsigned int p2 = (unsigned int)__shfl_xor((int)v16, 2);
      unsigned int v32 = (q & 2) ? (p2 | (v16 << 16)) : (v16 | (p2 << 16));
      unsigned int p3 = (unsigned int)__shfl_xor((int)v32, 4);
      vw[r][0] = (q & 4) ? p3 : v32;
      vw[r][1] = (q & 4) ? v32 : p3;
    }
  }

  // term1 of fe_model, once per pair
  if (q == 0)
    fe += bs * (float)(__popc(vw[0][0]) + __popc(vw[0][1]) +
                       __popc(vw[1][0]) + __popc(vw[1][1]));

  // wave reduction, one atomic per wave
  for (int off = 32; off > 0; off >>= 1) fe += __shfl_down(fe, off);
  if ((tid & 63) == 0) atomicAdd(ws, fe);
}

__global__ void fin_kernel(const float* __restrict__ ws, float* __restrict__ out) {
  out[0] = ws[0] * (1.0f / 65536.0f);
}

extern "C" void kernel_launch(void* const* d_in, const int* in_sizes, int n_in,
                              void* d_out, int out_size, void* d_ws, size_t ws_size,
                              hipStream_t stream)
{
  (void)in_sizes; (void)n_in; (void)out_size; (void)ws_size;
  const float* vdat = (const float*)d_in[0];
  const float* kf   = (const float*)d_in[1];
  const float* bsp  = (const float*)d_in[2];
  const float* cvp  = (const float*)d_in[3];
  float* out = (float*)d_out;
  float* ws  = (float*)d_ws;

  init_ws_kernel<<<dim3(1), dim3(1), 0, stream>>>(ws);
  rbm_valu_kernel<<<dim3(1024), dim3(256), 0, stream>>>(vdat, kf, bsp, cvp, ws);
  fin_kernel<<<dim3(1), dim3(1), 0, stream>>>(ws, out);
}